// Round 12
// baseline (480.707 us; speedup 1.0000x reference)
//
#include <hip/hip_runtime.h>

typedef short bf16x8 __attribute__((ext_vector_type(8)));
typedef float f32x4 __attribute__((ext_vector_type(4)));
typedef float f32x16 __attribute__((ext_vector_type(16)));
typedef unsigned int u32x4 __attribute__((ext_vector_type(4)));

#define KVP 1152  // 1101 kv rows padded to 18*64

__device__ __forceinline__ unsigned short f2b(float f) {
    unsigned int u = __float_as_uint(f);
    u += 0x7FFFu + ((u >> 16) & 1u);
    return (unsigned short)(u >> 16);
}

__device__ __forceinline__ f32x4 mfma16(bf16x8 a, bf16x8 b, f32x4 c) {
    return __builtin_amdgcn_mfma_f32_16x16x32_bf16(a, b, c, 0, 0, 0);
}
__device__ __forceinline__ f32x16 mfma32(bf16x8 a, bf16x8 b, f32x16 c) {
    return __builtin_amdgcn_mfma_f32_32x32x16_bf16(a, b, c, 0, 0, 0);
}
__device__ __forceinline__ float exp2_raw(float x) {
    float r; asm("v_exp_f32 %0, %1" : "=v"(r) : "v"(x)); return r;
}
__device__ __forceinline__ unsigned cvt_pk(float lo, float hi) {
    unsigned r; asm("v_cvt_pk_bf16_f32 %0, %1, %2" : "=v"(r) : "v"(lo), "v"(hi)); return r;
}
__device__ __forceinline__ float f3(float a, float b, float c) { return fmaxf(fmaxf(a, b), c); }

typedef __attribute__((address_space(3))) unsigned int lds_u32_t;
typedef const __attribute__((address_space(1))) unsigned int glb_u32_t;
__device__ __forceinline__ void async_cp16(const void* g, void* l) {
    __builtin_amdgcn_global_load_lds((glb_u32_t*)(unsigned long long)g,
                                     (lds_u32_t*)(unsigned int)(unsigned long long)l,
                                     16, 0, 0);
}

// ------- fused: GroupNorm partial sums (blocks 0..511) + f32->bf16 converts (rest) -------
__global__ __launch_bounds__(256) void prep_k(const float* __restrict__ x, float2* __restrict__ part,
                                              const float* __restrict__ a, unsigned short* __restrict__ oa,
                                              const float* __restrict__ b, unsigned short* __restrict__ ob,
                                              const float* __restrict__ c, unsigned short* __restrict__ oc,
                                              const float* __restrict__ d, unsigned short* __restrict__ od) {
    if (blockIdx.x < 512) {
        int blk = blockIdx.x;
        const float4* p = (const float4*)(x + (size_t)blk * 16384);
        float s = 0.f, ss = 0.f;
        for (int i = threadIdx.x; i < 4096; i += 256) {
            float4 v = p[i];
            s  += v.x + v.y + v.z + v.w;
            ss += v.x * v.x + v.y * v.y + v.z * v.z + v.w * v.w;
        }
#pragma unroll
        for (int o = 32; o; o >>= 1) { s += __shfl_down(s, o); ss += __shfl_down(ss, o); }
        __shared__ float red[8];
        int w = threadIdx.x >> 6;
        if ((threadIdx.x & 63) == 0) { red[w] = s; red[4 + w] = ss; }
        __syncthreads();
        if (threadIdx.x == 0) {
            s  = red[0] + red[1] + red[2] + red[3];
            ss = red[4] + red[5] + red[6] + red[7];
            part[blk] = make_float2(s, ss);
        }
        return;
    }
    int i = (blockIdx.x - 512) * 256 + threadIdx.x;
    const float* src; unsigned short* dst; int j;
    if (i < 196608)      { src = a; dst = oa; j = i; }
    else if (i < 393216) { src = b; dst = ob; j = i - 196608; }
    else if (i < 458752) { src = c; dst = oc; j = i - 393216; }
    else if (i < 695296) { src = d; dst = od; j = i - 458752; }
    else return;
    float4 v = ((const float4*)src)[j];
    uint2 u = make_uint2(cvt_pk(v.x, v.y), cvt_pk(v.z, v.w));
    ((uint2*)dst)[j] = u;
}

// ------------- GN apply + transpose [B,C,HW] -> bf16 tokens [B,HW,C] (64x64 tiles) -------------
__global__ __launch_bounds__(256) void gn_apply_k(const float* __restrict__ x, const float2* __restrict__ part,
                                                  const float* __restrict__ gamma, const float* __restrict__ beta,
                                                  unsigned short* __restrict__ xt) {
    int st = blockIdx.x & 15;
    int ct = (blockIdx.x >> 4) & 7;
    int b  = blockIdx.x >> 7;
    int bg = b * 8 + ct;
    float2 p0 = part[4 * bg], p1 = part[4 * bg + 1], p2 = part[4 * bg + 2], p3 = part[4 * bg + 3];
    float s = (p0.x + p1.x) + (p2.x + p3.x);
    float ss = (p0.y + p1.y) + (p2.y + p3.y);
    float mean = s * (1.f / 65536.f);
    float var  = ss * (1.f / 65536.f) - mean * mean;
    float rsig = rsqrtf(var + 1e-5f);
    __shared__ unsigned short tile[64][65];
    int tid = threadIdx.x;
#pragma unroll
    for (int it = 0; it < 4; ++it) {
        int idx = it * 256 + tid;
        int ci = idx >> 4, j4 = idx & 15;
        int c = ct * 64 + ci;
        float4 v = *(const float4*)(x + ((size_t)b * 512 + c) * 1024 + st * 64 + j4 * 4);
        float gs = gamma[c] * rsig;
        float bo = beta[c] - mean * gs;
        tile[j4 * 4 + 0][ci] = f2b(v.x * gs + bo);
        tile[j4 * 4 + 1][ci] = f2b(v.y * gs + bo);
        tile[j4 * 4 + 2][ci] = f2b(v.z * gs + bo);
        tile[j4 * 4 + 3][ci] = f2b(v.w * gs + bo);
    }
    __syncthreads();
#pragma unroll
    for (int it = 0; it < 4; ++it) {
        int idx = it * 256 + tid;
        int si = idx >> 4, q = idx & 15;
        uint2 u;
        u.x = (unsigned)tile[si][q * 4 + 0] | ((unsigned)tile[si][q * 4 + 1] << 16);
        u.y = (unsigned)tile[si][q * 4 + 2] | ((unsigned)tile[si][q * 4 + 3] << 16);
        *(uint2*)(xt + ((size_t)b * 1024 + st * 64 + si) * 512 + ct * 64 + q * 4) = u;
    }
}

// ----- 256x128-tile NT GEMM: 8 waves, BK=32, 3 LDS bufs, counted-vmcnt depth 2 -----
// r12: MINW template arg -> __launch_bounds__(512, MINW). MINW=4 caps unified regs at
// 128/wave (64 AGPR acc + <=64 VGPR) so 2 blocks/CU co-reside (16 waves) -- the r8-r11
// occupancy analysis missed that AGPRs count against the same budget (152/wave = 1 block).
template <int EPI, int MINW>
__global__ __launch_bounds__(512, MINW) void gemm256_k(const unsigned short* __restrict__ A,
                                                 const unsigned short* __restrict__ Bw,
                                                 const float* __restrict__ bias,
                                                 int K,
                                                 unsigned short* __restrict__ Qo,
                                                 unsigned short* __restrict__ Ko,
                                                 unsigned short* __restrict__ Vo,
                                                 const float* __restrict__ x0,
                                                 float* __restrict__ outp) {
    __shared__ __align__(16) unsigned short As[3][8192];
    __shared__ __align__(16) unsigned short Bs[3][4096];
    const int m0 = blockIdx.x * 256, n0 = blockIdx.y * 128;
    const bool swp = (EPI == 0) && (blockIdx.y < 8);
    const int tid = threadIdx.x, lane = tid & 63, w = tid >> 6;
    const int wr = w >> 1, wc = w & 1;
    const int lc = lane & 15, lg = lane >> 4;

    const int sRow = lane >> 2;
    const int sSlot = (lane & 3) ^ ((lane >> 3) & 3);
    const unsigned short* aSrc0 = A + (size_t)(m0 + 16 * w + sRow) * K + sSlot * 8;
    const unsigned short* aSrc1 = A + (size_t)(m0 + 128 + 16 * w + sRow) * K + sSlot * 8;
    const unsigned short* bSrc0 = Bw + (size_t)(n0 + 16 * w + sRow) * K + sSlot * 8;

    const int rSlot8 = (lg ^ ((lc >> 1) & 3)) * 8;

    f32x4 acc[4][4];
#pragma unroll
    for (int m = 0; m < 4; ++m)
#pragma unroll
        for (int n = 0; n < 4; ++n) acc[m][n] = (f32x4){0.f, 0.f, 0.f, 0.f};

    const int nT = K >> 5;
    async_cp16(aSrc0, &As[0][w * 512]);
    async_cp16(aSrc1, &As[0][(8 + w) * 512]);
    async_cp16(bSrc0, &Bs[0][w * 512]);
    async_cp16(aSrc0 + 32, &As[1][w * 512]);
    async_cp16(aSrc1 + 32, &As[1][(8 + w) * 512]);
    async_cp16(bSrc0 + 32, &Bs[1][w * 512]);

    int c = 0;
#pragma unroll 1
    for (int t = 0; t < nT; ++t) {
        if (t + 2 < nT) {
            int c2 = c + 2; if (c2 >= 3) c2 -= 3;
            const int k2 = (t + 2) << 5;
            async_cp16(aSrc0 + k2, &As[c2][w * 512]);
            async_cp16(aSrc1 + k2, &As[c2][(8 + w) * 512]);
            async_cp16(bSrc0 + k2, &Bs[c2][w * 512]);
            asm volatile("s_waitcnt vmcnt(6)" ::: "memory");
        } else if (t + 1 < nT) {
            asm volatile("s_waitcnt vmcnt(3)" ::: "memory");
        } else {
            asm volatile("s_waitcnt vmcnt(0)" ::: "memory");
        }
        __builtin_amdgcn_s_barrier();   // tile t landed (everyone)

        bf16x8 af[4], bfr[4];
#pragma unroll
        for (int m = 0; m < 4; ++m)
            af[m] = *(const bf16x8*)&As[c][(wr * 64 + m * 16 + lc) * 32 + rSlot8];
#pragma unroll
        for (int n = 0; n < 4; ++n)
            bfr[n] = *(const bf16x8*)&Bs[c][(wc * 64 + n * 16 + lc) * 32 + rSlot8];

        __builtin_amdgcn_s_setprio(1);
        if (swp) {
#pragma unroll
            for (int m = 0; m < 4; ++m)
#pragma unroll
                for (int n = 0; n < 4; ++n)
                    acc[m][n] = mfma16(bfr[n], af[m], acc[m][n]);   // C^T
        } else {
#pragma unroll
            for (int m = 0; m < 4; ++m)
#pragma unroll
                for (int n = 0; n < 4; ++n)
                    acc[m][n] = mfma16(af[m], bfr[n], acc[m][n]);   // C
        }
        __builtin_amdgcn_s_setprio(0);
        __builtin_amdgcn_s_barrier();   // all reads of buf[c] consumed -> reusable

        ++c; if (c == 3) c = 0;
    }

    if (EPI == 0) {
        if (swp) {
            const bool isQ = (n0 < 512);
            const float sc = isQ ? (0.125f * 1.44269504089f) : 1.f;
#pragma unroll
            for (int n = 0; n < 4; ++n) {
                const int c0 = n0 + wc * 64 + n * 16 + lg * 4;
                const float4 b4 = *(const float4*)&bias[c0];
#pragma unroll
                for (int m = 0; m < 4; ++m) {
                    const int tok = m0 + wr * 64 + m * 16 + lc;
                    const int b = tok >> 10, l = tok & 1023;
                    float v0 = (acc[m][n][0] + b4.x) * sc;
                    float v1 = (acc[m][n][1] + b4.y) * sc;
                    float v2 = (acc[m][n][2] + b4.z) * sc;
                    float v3 = (acc[m][n][3] + b4.w) * sc;
                    uint2 u = make_uint2(cvt_pk(v0, v1), cvt_pk(v2, v3));
                    if (isQ) {
                        const int hh = c0 >> 6, d = c0 & 63;
                        *(uint2*)(Qo + ((size_t)(b * 8 + hh) * 1024 + l) * 64 + d) = u;
                    } else {
                        const int hh = (c0 - 512) >> 6, d = c0 & 63;
                        *(uint2*)(Ko + ((size_t)(b * 8 + hh) * KVP + l) * 64 + d) = u;
                    }
                }
            }
        } else {
#pragma unroll
            for (int n = 0; n < 4; ++n) {
                const int col = n0 + wc * 64 + n * 16 + lc;
                const int j = col - 1024;
                const int hh = j >> 6, d = j & 63;
                const float bv = bias[col];
#pragma unroll
                for (int m = 0; m < 4; ++m) {
                    const int t0 = m0 + wr * 64 + m * 16 + lg * 4;
                    const int b = t0 >> 10, l0 = t0 & 1023;
                    uint2 u = make_uint2(cvt_pk(acc[m][n][0] + bv, acc[m][n][1] + bv),
                                         cvt_pk(acc[m][n][2] + bv, acc[m][n][3] + bv));
                    *(uint2*)(Vo + ((size_t)(b * 8 + hh) * 64 + d) * KVP + l0) = u;
                }
            }
        }
    } else {
#pragma unroll
        for (int n = 0; n < 4; ++n) {
            const int col = n0 + wc * 64 + n * 16 + lc;
            const float bv = bias[col];
#pragma unroll
            for (int m = 0; m < 4; ++m) {
                const int t0 = m0 + wr * 64 + m * 16 + lg * 4;
                const size_t a = ((size_t)(t0 >> 10) * 512 + col) * 1024 + (t0 & 1023);
                float4 xv = *(const float4*)(x0 + a);
                float4 o;
                o.x = acc[m][n][0] + bv + xv.x;
                o.y = acc[m][n][1] + bv + xv.y;
                o.z = acc[m][n][2] + bv + xv.z;
                o.w = acc[m][n][3] + bv + xv.w;
                *(float4*)(outp + a) = o;
            }
        }
    }
}

// ---------------- 64-tile NT GEMM (cond KV only; M not tile-exact) ----------------
__global__ __launch_bounds__(256) void gemm_nt_k(const unsigned short* __restrict__ A,
                                                 const unsigned short* __restrict__ Bw,
                                                 const float* __restrict__ bias,
                                                 int M, int N, int K,
                                                 unsigned short* __restrict__ Ko,
                                                 unsigned short* __restrict__ Vo) {
    __shared__ unsigned short As[64][40];
    __shared__ unsigned short Bs[64][40];
    const int m0 = blockIdx.x * 64, n0 = blockIdx.y * 64;
    const int tid = threadIdx.x, lane = tid & 63, w = tid >> 6;
    const int lc = lane & 15, lg = lane >> 4;
    const int lrow = tid >> 2, lseg = tid & 3;
    f32x4 acc[4];
#pragma unroll
    for (int i = 0; i < 4; ++i) acc[i] = (f32x4){0.f, 0.f, 0.f, 0.f};

    for (int k0 = 0; k0 < K; k0 += 32) {
        uint4 av = make_uint4(0u, 0u, 0u, 0u);
        if (m0 + lrow < M) av = *(const uint4*)(A + (size_t)(m0 + lrow) * K + k0 + lseg * 8);
        *(uint4*)&As[lrow][lseg * 8] = av;
        uint4 bv = *(const uint4*)(Bw + (size_t)(n0 + lrow) * K + k0 + lseg * 8);
        *(uint4*)&Bs[lrow][lseg * 8] = bv;
        __syncthreads();
        bf16x8 af = *(const bf16x8*)&As[w * 16 + lc][lg * 8];
#pragma unroll
        for (int ct = 0; ct < 4; ++ct) {
            bf16x8 bfr = *(const bf16x8*)&Bs[ct * 16 + lc][lg * 8];
            acc[ct] = mfma16(af, bfr, acc[ct]);
        }
        __syncthreads();
    }

    const int rbase = m0 + w * 16 + lg * 4;
#pragma unroll
    for (int ct = 0; ct < 4; ++ct) {
        int col = n0 + ct * 16 + lc;
        float bv = bias[col];
#pragma unroll
        for (int r = 0; r < 4; ++r) {
            int token = rbase + r;
            if (token >= M) continue;
            float val = acc[ct][r] + bv;
            int b = token / 77, l = token - b * 77;
            if (col < 512) {
                int hh = col >> 6, d = col & 63;
                Ko[((size_t)(b * 8 + hh) * KVP + 1024 + l) * 64 + d] = f2b(val);
            } else {
                int j = col - 512, hh = j >> 6, d = j & 63;
                Vo[((size_t)(b * 8 + hh) * 64 + d) * KVP + 1024 + l] = f2b(val);
            }
        }
    }
}

// ---- attention: 8 waves/block, 32 q-rows/wave, swapped QK^T, KVBLK=64, XCD-friendly decode ----
__global__ __launch_bounds__(512) void attn2_k(const unsigned short* __restrict__ Q,
                                               const unsigned short* __restrict__ Kb,
                                               const unsigned short* __restrict__ Vt,
                                               unsigned short* __restrict__ atok) {
    __shared__ __align__(16) unsigned short lds[18432];

    const int bid = blockIdx.x;
    const int bh = bid & 127;
    const int qt = bid >> 7;
    const int w  = threadIdx.x >> 6;
    const int lane = threadIdx.x & 63;
    const int ql = lane & 31, hi = lane >> 5;
    const int q0 = qt * 256 + w * 32;

    bf16x8 qf[4];
    const unsigned short* Qp = Q + ((size_t)bh * 1024 + q0 + ql) * 64 + hi * 8;
#pragma unroll
    for (int ks = 0; ks < 4; ++ks) qf[ks] = *(const bf16x8*)(Qp + ks * 16);

    const unsigned short* Kg = Kb + (size_t)bh * KVP * 64;
    const unsigned short* Vg = Vt + (size_t)bh * 64 * KVP;

    const int srow = lane >> 3;
    const int sc   = (((lane & 7) ^ (lane >> 3)) << 3);

    f32x16 o0, o1;
#pragma unroll
    for (int i = 0; i < 16; ++i) { o0[i] = 0.f; o1[i] = 0.f; }
    float mreg = -1e30f, lsum = 0.f;

    {
        uint4 kr = *(const uint4*)(Kg + (size_t)(8 * w + srow) * 64 + sc);
        uint4 vr = *(const uint4*)(Vg + (size_t)(8 * w + srow) * KVP + sc);
        *(uint4*)&lds[w * 512 + lane * 8] = kr;
        *(uint4*)&lds[4096 + w * 512 + lane * 8] = vr;
    }
    __syncthreads();

    int cur = 0;
    for (int it = 0; it < 18; ++it) {
        const int kv0 = it * 64;
        const bool pre = (it < 17);
        uint4 kn, vn;
        if (pre) {
            kn = *(const uint4*)(Kg + (size_t)(kv0 + 64 + 8 * w + srow) * 64 + sc);
            vn = *(const uint4*)(Vg + (size_t)(8 * w + srow) * KVP + kv0 + 64 + sc);
        }
        const int kb = cur * 8192, vb = cur * 8192 + 4096;

        f32x16 s0, s1;
#pragma unroll
        for (int i = 0; i < 16; ++i) { s0[i] = 0.f; s1[i] = 0.f; }
        __builtin_amdgcn_s_setprio(1);
#pragma unroll
        for (int ks = 0; ks < 4; ++ks) {
            const int sl = ((ks * 2 + hi) ^ (ql & 7)) << 3;
            bf16x8 kf0 = *(const bf16x8*)&lds[kb + ql * 64 + sl];
            bf16x8 kf1 = *(const bf16x8*)&lds[kb + (32 + ql) * 64 + sl];
            s0 = mfma32(kf0, qf[ks], s0);
            s1 = mfma32(kf1, qf[ks], s1);
        }
        __builtin_amdgcn_s_setprio(0);
        if (kv0 == 1088) {
#pragma unroll
            for (int r = 0; r < 16; ++r) {
                int kva = 1088 + (r & 3) + 8 * (r >> 2) + 4 * hi;
                if (kva >= 1101) s0[r] = -1e30f;
                if (kva + 32 >= 1101) s1[r] = -1e30f;
            }
        }

        float t[16];
#pragma unroll
        for (int i = 0; i < 16; ++i) t[i] = fmaxf(s0[i], s1[i]);
        float a0m = f3(t[0], t[1], t[2]),  a1m = f3(t[3], t[4], t[5]);
        float a2m = f3(t[6], t[7], t[8]),  a3m = f3(t[9], t[10], t[11]);
        float a4m = f3(t[12], t[13], t[14]);
        float pm  = fmaxf(f3(a0m, a1m, a2m), f3(a3m, a4m, t[15]));
        float pmax = fmaxf(pm, __shfl_xor(pm, 32));

        if (__any(pmax > mreg + 8.f)) {
            float mn = fmaxf(mreg, pmax);
            float al = exp2_raw(mreg - mn);
            mreg = mn;
            lsum *= al;
#pragma unroll
            for (int i = 0; i < 16; ++i) { o0[i] *= al; o1[i] *= al; }
        }

        unsigned pk0[8], pk1[8];
        float sA = 0.f, sB = 0.f, sC = 0.f, sD = 0.f;
#pragma unroll
        for (int i = 0; i < 8; ++i) {
            float a0 = exp2_raw(s0[2 * i] - mreg), a1 = exp2_raw(s0[2 * i + 1] - mreg);
            float b0 = exp2_raw(s1[2 * i] - mreg), b1 = exp2_raw(s1[2 * i + 1] - mreg);
            pk0[i] = cvt_pk(a0, a1);
            pk1[i] = cvt_pk(b0, b1);
            sA += a0; sB += a1; sC += b0; sD += b1;
        }
        float ls = (sA + sB) + (sC + sD);
        ls += __shfl_xor(ls, 32);
        lsum += ls;

#pragma unroll
        for (int t2 = 0; t2 < 2; ++t2) {
            const unsigned* pk = t2 ? pk1 : pk0;
#pragma unroll
            for (int v = 0; v < 2; ++v) {
                unsigned a0 = pk[4 * v], a1 = pk[4 * v + 1], a2 = pk[4 * v + 2], a3 = pk[4 * v + 3];
                unsigned x = __shfl_xor(hi ? a0 : a2, 32);
                unsigned y = __shfl_xor(hi ? a1 : a3, 32);
                u32x4 fw;
                fw.x = hi ? x : a0; fw.y = hi ? y : a1; fw.z = hi ? a2 : x; fw.w = hi ? a3 : y;
                bf16x8 pf = __builtin_bit_cast(bf16x8, fw);
                const int ks2 = 2 * t2 + v;
                const int sl = ((ks2 * 2 + hi) ^ (ql & 7)) << 3;
                bf16x8 vf0 = *(const bf16x8*)&lds[vb + ql * 64 + sl];
                bf16x8 vf1 = *(const bf16x8*)&lds[vb + (32 + ql) * 64 + sl];
                __builtin_amdgcn_s_setprio(1);
                o0 = mfma32(vf0, pf, o0);
                o1 = mfma32(vf1, pf, o1);
                __builtin_amdgcn_s_setprio(0);
            }
        }

        if (pre) {
            *(uint4*)&lds[(cur ^ 1) * 8192 + w * 512 + lane * 8] = kn;
            *(uint4*)&lds[(cur ^ 1) * 8192 + 4096 + w * 512 + lane * 8] = vn;
        }
        __syncthreads();
        cur ^= 1;
    }

    float rinv = 1.f / lsum;
    unsigned short* sw = &lds[w * 2304];
#pragma unroll
    for (int dt = 0; dt < 2; ++dt) {
#pragma unroll
        for (int rp = 0; rp < 8; ++rp) {
            float e0 = (dt ? o1[2 * rp] : o0[2 * rp]) * rinv;
            float e1 = (dt ? o1[2 * rp + 1] : o0[2 * rp + 1]) * rinv;
            int d = dt * 32 + ((2 * rp) & 3) + 8 * ((2 * rp) >> 2) + 4 * hi;
            *(unsigned*)&sw[ql * 72 + d] = cvt_pk(e0, e1);
        }
    }
    __syncthreads();
    {
        int i = threadIdx.x >> 1, hf = threadIdx.x & 1;
        const unsigned short* src = &lds[(i >> 5) * 2304 + (i & 31) * 72 + hf * 32];
        u32x4 r0 = *(const u32x4*)(src);
        u32x4 r1 = *(const u32x4*)(src + 8);
        u32x4 r2 = *(const u32x4*)(src + 16);
        u32x4 r3 = *(const u32x4*)(src + 24);
        int b = bh >> 3, h = bh & 7;
        unsigned short* gd = atok + ((size_t)b * 1024 + qt * 256 + i) * 512 + h * 64 + hf * 32;
        *(u32x4*)(gd) = r0;
        *(u32x4*)(gd + 8) = r1;
        *(u32x4*)(gd + 16) = r2;
        *(u32x4*)(gd + 24) = r3;
    }
}

extern "C" void kernel_launch(void* const* d_in, const int* in_sizes, int n_in,
                              void* d_out, int out_size, void* d_ws, size_t ws_size,
                              hipStream_t stream) {
    const float* x0     = (const float*)d_in[0];
    const float* cond   = (const float*)d_in[1];
    const float* gamma  = (const float*)d_in[2];
    const float* beta   = (const float*)d_in[3];
    const float* qkv_w  = (const float*)d_in[4];
    const float* qkv_b  = (const float*)d_in[5];
    const float* ckv_w  = (const float*)d_in[6];
    const float* ckv_b  = (const float*)d_in[7];
    const float* out_w  = (const float*)d_in[8];
    const float* out_b  = (const float*)d_in[9];
    float* outp = (float*)d_out;

    char* p = (char*)d_ws;
    float2* part = (float2*)p;           p += 4096;
    unsigned short* xt    = (unsigned short*)p; p += (size_t)16384 * 512 * 2;
    unsigned short* wqkv  = (unsigned short*)p; p += (size_t)1536 * 512 * 2;
    unsigned short* wckv  = (unsigned short*)p; p += (size_t)1024 * 768 * 2;
    unsigned short* wout  = (unsigned short*)p; p += (size_t)512 * 512 * 2;
    unsigned short* condb = (unsigned short*)p; p += (size_t)1232 * 768 * 2;
    unsigned short* Qb    = (unsigned short*)p; p += (size_t)16 * 8 * 1024 * 64 * 2;
    unsigned short* Kb    = (unsigned short*)p; p += (size_t)16 * 8 * KVP * 64 * 2;
    unsigned short* Vtb   = (unsigned short*)p; p += (size_t)16 * 8 * KVP * 64 * 2;
    unsigned short* atok  = (unsigned short*)p; p += (size_t)16384 * 512 * 2;

    prep_k<<<512 + 2716, 256, 0, stream>>>(x0, part, qkv_w, wqkv, ckv_w, wckv, out_w, wout, cond, condb);
    gn_apply_k<<<2048, 256, 0, stream>>>(x0, part, gamma, beta, xt);

    // fused QKV GEMM: y 0..7 -> Q/K, y 8..11 -> V ; MINW=4 -> 2 blocks/CU
    gemm256_k<0, 4><<<dim3(64, 12), 512, 0, stream>>>(xt, wqkv, qkv_b, 512,
                                                      Qb, Kb, Vtb, nullptr, nullptr);
    gemm_nt_k<<<dim3(20, 16), 256, 0, stream>>>(condb, wckv, ckv_b, 1232, 1024, 768, Kb, Vtb);
    attn2_k<<<512, 512, 0, stream>>>(Qb, Kb, Vtb, atok);
    gemm256_k<2, 2><<<dim3(64, 4), 512, 0, stream>>>(atok, wout, out_b, 512,
                                                     nullptr, nullptr, nullptr, x0, outp);
}

// Round 13
// 172.441 us; speedup vs baseline: 2.7877x; 2.7877x over previous
//
#include <hip/hip_runtime.h>

typedef short bf16x8 __attribute__((ext_vector_type(8)));
typedef float f32x4 __attribute__((ext_vector_type(4)));
typedef float f32x16 __attribute__((ext_vector_type(16)));
typedef unsigned int u32x4 __attribute__((ext_vector_type(4)));

#define KVP 1152  // 1101 kv rows padded to 18*64

__device__ __forceinline__ unsigned short f2b(float f) {
    unsigned int u = __float_as_uint(f);
    u += 0x7FFFu + ((u >> 16) & 1u);
    return (unsigned short)(u >> 16);
}

__device__ __forceinline__ f32x4 mfma16(bf16x8 a, bf16x8 b, f32x4 c) {
    return __builtin_amdgcn_mfma_f32_16x16x32_bf16(a, b, c, 0, 0, 0);
}
__device__ __forceinline__ f32x16 mfma32(bf16x8 a, bf16x8 b, f32x16 c) {
    return __builtin_amdgcn_mfma_f32_32x32x16_bf16(a, b, c, 0, 0, 0);
}
__device__ __forceinline__ float exp2_raw(float x) {
    float r; asm("v_exp_f32 %0, %1" : "=v"(r) : "v"(x)); return r;
}
__device__ __forceinline__ unsigned cvt_pk(float lo, float hi) {
    unsigned r; asm("v_cvt_pk_bf16_f32 %0, %1, %2" : "=v"(r) : "v"(lo), "v"(hi)); return r;
}
__device__ __forceinline__ float f3(float a, float b, float c) { return fmaxf(fmaxf(a, b), c); }

typedef __attribute__((address_space(3))) unsigned int lds_u32_t;
typedef const __attribute__((address_space(1))) unsigned int glb_u32_t;
__device__ __forceinline__ void async_cp16(const void* g, void* l) {
    __builtin_amdgcn_global_load_lds((glb_u32_t*)(unsigned long long)g,
                                     (lds_u32_t*)(unsigned int)(unsigned long long)l,
                                     16, 0, 0);
}

// ------- fused: GroupNorm partial sums (blocks 0..511) + f32->bf16 converts (rest) -------
__global__ __launch_bounds__(256) void prep_k(const float* __restrict__ x, float2* __restrict__ part,
                                              const float* __restrict__ a, unsigned short* __restrict__ oa,
                                              const float* __restrict__ b, unsigned short* __restrict__ ob,
                                              const float* __restrict__ c, unsigned short* __restrict__ oc,
                                              const float* __restrict__ d, unsigned short* __restrict__ od) {
    if (blockIdx.x < 512) {
        int blk = blockIdx.x;
        const float4* p = (const float4*)(x + (size_t)blk * 16384);
        float s = 0.f, ss = 0.f;
        for (int i = threadIdx.x; i < 4096; i += 256) {
            float4 v = p[i];
            s  += v.x + v.y + v.z + v.w;
            ss += v.x * v.x + v.y * v.y + v.z * v.z + v.w * v.w;
        }
#pragma unroll
        for (int o = 32; o; o >>= 1) { s += __shfl_down(s, o); ss += __shfl_down(ss, o); }
        __shared__ float red[8];
        int w = threadIdx.x >> 6;
        if ((threadIdx.x & 63) == 0) { red[w] = s; red[4 + w] = ss; }
        __syncthreads();
        if (threadIdx.x == 0) {
            s  = red[0] + red[1] + red[2] + red[3];
            ss = red[4] + red[5] + red[6] + red[7];
            part[blk] = make_float2(s, ss);
        }
        return;
    }
    int i = (blockIdx.x - 512) * 256 + threadIdx.x;
    const float* src; unsigned short* dst; int j;
    if (i < 196608)      { src = a; dst = oa; j = i; }
    else if (i < 393216) { src = b; dst = ob; j = i - 196608; }
    else if (i < 458752) { src = c; dst = oc; j = i - 393216; }
    else if (i < 695296) { src = d; dst = od; j = i - 458752; }
    else return;
    float4 v = ((const float4*)src)[j];
    uint2 u = make_uint2(cvt_pk(v.x, v.y), cvt_pk(v.z, v.w));
    ((uint2*)dst)[j] = u;
}

// ------------- GN apply + transpose [B,C,HW] -> bf16 tokens [B,HW,C] (64x64 tiles) -------------
__global__ __launch_bounds__(256) void gn_apply_k(const float* __restrict__ x, const float2* __restrict__ part,
                                                  const float* __restrict__ gamma, const float* __restrict__ beta,
                                                  unsigned short* __restrict__ xt) {
    int st = blockIdx.x & 15;
    int ct = (blockIdx.x >> 4) & 7;
    int b  = blockIdx.x >> 7;
    int bg = b * 8 + ct;
    float2 p0 = part[4 * bg], p1 = part[4 * bg + 1], p2 = part[4 * bg + 2], p3 = part[4 * bg + 3];
    float s = (p0.x + p1.x) + (p2.x + p3.x);
    float ss = (p0.y + p1.y) + (p2.y + p3.y);
    float mean = s * (1.f / 65536.f);
    float var  = ss * (1.f / 65536.f) - mean * mean;
    float rsig = rsqrtf(var + 1e-5f);
    __shared__ unsigned short tile[64][65];
    int tid = threadIdx.x;
#pragma unroll
    for (int it = 0; it < 4; ++it) {
        int idx = it * 256 + tid;
        int ci = idx >> 4, j4 = idx & 15;
        int c = ct * 64 + ci;
        float4 v = *(const float4*)(x + ((size_t)b * 512 + c) * 1024 + st * 64 + j4 * 4);
        float gs = gamma[c] * rsig;
        float bo = beta[c] - mean * gs;
        tile[j4 * 4 + 0][ci] = f2b(v.x * gs + bo);
        tile[j4 * 4 + 1][ci] = f2b(v.y * gs + bo);
        tile[j4 * 4 + 2][ci] = f2b(v.z * gs + bo);
        tile[j4 * 4 + 3][ci] = f2b(v.w * gs + bo);
    }
    __syncthreads();
#pragma unroll
    for (int it = 0; it < 4; ++it) {
        int idx = it * 256 + tid;
        int si = idx >> 4, q = idx & 15;
        uint2 u;
        u.x = (unsigned)tile[si][q * 4 + 0] | ((unsigned)tile[si][q * 4 + 1] << 16);
        u.y = (unsigned)tile[si][q * 4 + 2] | ((unsigned)tile[si][q * 4 + 3] << 16);
        *(uint2*)(xt + ((size_t)b * 1024 + st * 64 + si) * 512 + ct * 64 + q * 4) = u;
    }
}

// ----- 256x128-tile NT GEMM: 8 waves, BK=32, 4 LDS bufs (96KB), counted-vmcnt depth 2,
// ----- SINGLE barrier per iter. WAR audit: stage at iter t overwrites buf[(t+2)&3] which
// ----- held tile t-2; any wave reaching iter t implies all waves passed barrier1(t-1),
// ----- by which their reads of tile t-2 were consumed (in-order issue). RAW: own vmcnt(6)
// ----- before barrier1 ensures tile t landed chip-wide after the barrier.
template <int EPI>
__global__ __launch_bounds__(512) void gemm256_k(const unsigned short* __restrict__ A,
                                                 const unsigned short* __restrict__ Bw,
                                                 const float* __restrict__ bias,
                                                 int K,
                                                 unsigned short* __restrict__ Qo,
                                                 unsigned short* __restrict__ Ko,
                                                 unsigned short* __restrict__ Vo,
                                                 const float* __restrict__ x0,
                                                 float* __restrict__ outp) {
    __shared__ __align__(16) unsigned short As[4][8192];
    __shared__ __align__(16) unsigned short Bs[4][4096];
    const int m0 = blockIdx.x * 256, n0 = blockIdx.y * 128;
    const bool swp = (EPI == 0) && (blockIdx.y < 8);
    const int tid = threadIdx.x, lane = tid & 63, w = tid >> 6;
    const int wr = w >> 1, wc = w & 1;
    const int lc = lane & 15, lg = lane >> 4;

    const int sRow = lane >> 2;
    const int sSlot = (lane & 3) ^ ((lane >> 3) & 3);
    const unsigned short* aSrc0 = A + (size_t)(m0 + 16 * w + sRow) * K + sSlot * 8;
    const unsigned short* aSrc1 = A + (size_t)(m0 + 128 + 16 * w + sRow) * K + sSlot * 8;
    const unsigned short* bSrc0 = Bw + (size_t)(n0 + 16 * w + sRow) * K + sSlot * 8;

    const int rSlot8 = (lg ^ ((lc >> 1) & 3)) * 8;

    f32x4 acc[4][4];
#pragma unroll
    for (int m = 0; m < 4; ++m)
#pragma unroll
        for (int n = 0; n < 4; ++n) acc[m][n] = (f32x4){0.f, 0.f, 0.f, 0.f};

    const int nT = K >> 5;
    async_cp16(aSrc0, &As[0][w * 512]);
    async_cp16(aSrc1, &As[0][(8 + w) * 512]);
    async_cp16(bSrc0, &Bs[0][w * 512]);
    async_cp16(aSrc0 + 32, &As[1][w * 512]);
    async_cp16(aSrc1 + 32, &As[1][(8 + w) * 512]);
    async_cp16(bSrc0 + 32, &Bs[1][w * 512]);

#pragma unroll 1
    for (int t = 0; t < nT; ++t) {
        const int c = t & 3;
        if (t + 2 < nT) {
            const int c2 = (t + 2) & 3;
            const int k2 = (t + 2) << 5;
            async_cp16(aSrc0 + k2, &As[c2][w * 512]);
            async_cp16(aSrc1 + k2, &As[c2][(8 + w) * 512]);
            async_cp16(bSrc0 + k2, &Bs[c2][w * 512]);
            asm volatile("s_waitcnt vmcnt(6)" ::: "memory");
        } else if (t + 1 < nT) {
            asm volatile("s_waitcnt vmcnt(3)" ::: "memory");
        } else {
            asm volatile("s_waitcnt vmcnt(0)" ::: "memory");
        }
        __builtin_amdgcn_s_barrier();   // tile t landed (everyone); sole barrier this iter

        bf16x8 af[4], bfr[4];
#pragma unroll
        for (int m = 0; m < 4; ++m)
            af[m] = *(const bf16x8*)&As[c][(wr * 64 + m * 16 + lc) * 32 + rSlot8];
#pragma unroll
        for (int n = 0; n < 4; ++n)
            bfr[n] = *(const bf16x8*)&Bs[c][(wc * 64 + n * 16 + lc) * 32 + rSlot8];

        __builtin_amdgcn_s_setprio(1);
        if (swp) {
#pragma unroll
            for (int m = 0; m < 4; ++m)
#pragma unroll
                for (int n = 0; n < 4; ++n)
                    acc[m][n] = mfma16(bfr[n], af[m], acc[m][n]);   // C^T
        } else {
#pragma unroll
            for (int m = 0; m < 4; ++m)
#pragma unroll
                for (int n = 0; n < 4; ++n)
                    acc[m][n] = mfma16(af[m], bfr[n], acc[m][n]);   // C
        }
        __builtin_amdgcn_s_setprio(0);
    }

    if (EPI == 0) {
        if (swp) {
            const bool isQ = (n0 < 512);
            const float sc = isQ ? (0.125f * 1.44269504089f) : 1.f;
#pragma unroll
            for (int n = 0; n < 4; ++n) {
                const int c0 = n0 + wc * 64 + n * 16 + lg * 4;
                const float4 b4 = *(const float4*)&bias[c0];
#pragma unroll
                for (int m = 0; m < 4; ++m) {
                    const int tok = m0 + wr * 64 + m * 16 + lc;
                    const int b = tok >> 10, l = tok & 1023;
                    float v0 = (acc[m][n][0] + b4.x) * sc;
                    float v1 = (acc[m][n][1] + b4.y) * sc;
                    float v2 = (acc[m][n][2] + b4.z) * sc;
                    float v3 = (acc[m][n][3] + b4.w) * sc;
                    uint2 u = make_uint2(cvt_pk(v0, v1), cvt_pk(v2, v3));
                    if (isQ) {
                        const int hh = c0 >> 6, d = c0 & 63;
                        *(uint2*)(Qo + ((size_t)(b * 8 + hh) * 1024 + l) * 64 + d) = u;
                    } else {
                        const int hh = (c0 - 512) >> 6, d = c0 & 63;
                        *(uint2*)(Ko + ((size_t)(b * 8 + hh) * KVP + l) * 64 + d) = u;
                    }
                }
            }
        } else {
#pragma unroll
            for (int n = 0; n < 4; ++n) {
                const int col = n0 + wc * 64 + n * 16 + lc;
                const int j = col - 1024;
                const int hh = j >> 6, d = j & 63;
                const float bv = bias[col];
#pragma unroll
                for (int m = 0; m < 4; ++m) {
                    const int t0 = m0 + wr * 64 + m * 16 + lg * 4;
                    const int b = t0 >> 10, l0 = t0 & 1023;
                    uint2 u = make_uint2(cvt_pk(acc[m][n][0] + bv, acc[m][n][1] + bv),
                                         cvt_pk(acc[m][n][2] + bv, acc[m][n][3] + bv));
                    *(uint2*)(Vo + ((size_t)(b * 8 + hh) * 64 + d) * KVP + l0) = u;
                }
            }
        }
    } else {
#pragma unroll
        for (int n = 0; n < 4; ++n) {
            const int col = n0 + wc * 64 + n * 16 + lc;
            const float bv = bias[col];
#pragma unroll
            for (int m = 0; m < 4; ++m) {
                const int t0 = m0 + wr * 64 + m * 16 + lg * 4;
                const size_t a = ((size_t)(t0 >> 10) * 512 + col) * 1024 + (t0 & 1023);
                float4 xv = *(const float4*)(x0 + a);
                float4 o;
                o.x = acc[m][n][0] + bv + xv.x;
                o.y = acc[m][n][1] + bv + xv.y;
                o.z = acc[m][n][2] + bv + xv.z;
                o.w = acc[m][n][3] + bv + xv.w;
                *(float4*)(outp + a) = o;
            }
        }
    }
}

// ---------------- 64-tile NT GEMM (cond KV only; M not tile-exact) ----------------
__global__ __launch_bounds__(256) void gemm_nt_k(const unsigned short* __restrict__ A,
                                                 const unsigned short* __restrict__ Bw,
                                                 const float* __restrict__ bias,
                                                 int M, int N, int K,
                                                 unsigned short* __restrict__ Ko,
                                                 unsigned short* __restrict__ Vo) {
    __shared__ unsigned short As[64][40];
    __shared__ unsigned short Bs[64][40];
    const int m0 = blockIdx.x * 64, n0 = blockIdx.y * 64;
    const int tid = threadIdx.x, lane = tid & 63, w = tid >> 6;
    const int lc = lane & 15, lg = lane >> 4;
    const int lrow = tid >> 2, lseg = tid & 3;
    f32x4 acc[4];
#pragma unroll
    for (int i = 0; i < 4; ++i) acc[i] = (f32x4){0.f, 0.f, 0.f, 0.f};

    for (int k0 = 0; k0 < K; k0 += 32) {
        uint4 av = make_uint4(0u, 0u, 0u, 0u);
        if (m0 + lrow < M) av = *(const uint4*)(A + (size_t)(m0 + lrow) * K + k0 + lseg * 8);
        *(uint4*)&As[lrow][lseg * 8] = av;
        uint4 bv = *(const uint4*)(Bw + (size_t)(n0 + lrow) * K + k0 + lseg * 8);
        *(uint4*)&Bs[lrow][lseg * 8] = bv;
        __syncthreads();
        bf16x8 af = *(const bf16x8*)&As[w * 16 + lc][lg * 8];
#pragma unroll
        for (int ct = 0; ct < 4; ++ct) {
            bf16x8 bfr = *(const bf16x8*)&Bs[ct * 16 + lc][lg * 8];
            acc[ct] = mfma16(af, bfr, acc[ct]);
        }
        __syncthreads();
    }

    const int rbase = m0 + w * 16 + lg * 4;
#pragma unroll
    for (int ct = 0; ct < 4; ++ct) {
        int col = n0 + ct * 16 + lc;
        float bv = bias[col];
#pragma unroll
        for (int r = 0; r < 4; ++r) {
            int token = rbase + r;
            if (token >= M) continue;
            float val = acc[ct][r] + bv;
            int b = token / 77, l = token - b * 77;
            if (col < 512) {
                int hh = col >> 6, d = col & 63;
                Ko[((size_t)(b * 8 + hh) * KVP + 1024 + l) * 64 + d] = f2b(val);
            } else {
                int j = col - 512, hh = j >> 6, d = j & 63;
                Vo[((size_t)(b * 8 + hh) * 64 + d) * KVP + 1024 + l] = f2b(val);
            }
        }
    }
}

// ---- attention: 8 waves/block, 32 q-rows/wave, swapped QK^T, KVBLK=64, XCD-friendly decode ----
__global__ __launch_bounds__(512) void attn2_k(const unsigned short* __restrict__ Q,
                                               const unsigned short* __restrict__ Kb,
                                               const unsigned short* __restrict__ Vt,
                                               unsigned short* __restrict__ atok) {
    __shared__ __align__(16) unsigned short lds[18432];

    const int bid = blockIdx.x;
    const int bh = bid & 127;
    const int qt = bid >> 7;
    const int w  = threadIdx.x >> 6;
    const int lane = threadIdx.x & 63;
    const int ql = lane & 31, hi = lane >> 5;
    const int q0 = qt * 256 + w * 32;

    bf16x8 qf[4];
    const unsigned short* Qp = Q + ((size_t)bh * 1024 + q0 + ql) * 64 + hi * 8;
#pragma unroll
    for (int ks = 0; ks < 4; ++ks) qf[ks] = *(const bf16x8*)(Qp + ks * 16);

    const unsigned short* Kg = Kb + (size_t)bh * KVP * 64;
    const unsigned short* Vg = Vt + (size_t)bh * 64 * KVP;

    const int srow = lane >> 3;
    const int sc   = (((lane & 7) ^ (lane >> 3)) << 3);

    f32x16 o0, o1;
#pragma unroll
    for (int i = 0; i < 16; ++i) { o0[i] = 0.f; o1[i] = 0.f; }
    float mreg = -1e30f, lsum = 0.f;

    {
        uint4 kr = *(const uint4*)(Kg + (size_t)(8 * w + srow) * 64 + sc);
        uint4 vr = *(const uint4*)(Vg + (size_t)(8 * w + srow) * KVP + sc);
        *(uint4*)&lds[w * 512 + lane * 8] = kr;
        *(uint4*)&lds[4096 + w * 512 + lane * 8] = vr;
    }
    __syncthreads();

    int cur = 0;
    for (int it = 0; it < 18; ++it) {
        const int kv0 = it * 64;
        const bool pre = (it < 17);
        uint4 kn, vn;
        if (pre) {
            kn = *(const uint4*)(Kg + (size_t)(kv0 + 64 + 8 * w + srow) * 64 + sc);
            vn = *(const uint4*)(Vg + (size_t)(8 * w + srow) * KVP + kv0 + 64 + sc);
        }
        const int kb = cur * 8192, vb = cur * 8192 + 4096;

        f32x16 s0, s1;
#pragma unroll
        for (int i = 0; i < 16; ++i) { s0[i] = 0.f; s1[i] = 0.f; }
        __builtin_amdgcn_s_setprio(1);
#pragma unroll
        for (int ks = 0; ks < 4; ++ks) {
            const int sl = ((ks * 2 + hi) ^ (ql & 7)) << 3;
            bf16x8 kf0 = *(const bf16x8*)&lds[kb + ql * 64 + sl];
            bf16x8 kf1 = *(const bf16x8*)&lds[kb + (32 + ql) * 64 + sl];
            s0 = mfma32(kf0, qf[ks], s0);
            s1 = mfma32(kf1, qf[ks], s1);
        }
        __builtin_amdgcn_s_setprio(0);
        if (kv0 == 1088) {
#pragma unroll
            for (int r = 0; r < 16; ++r) {
                int kva = 1088 + (r & 3) + 8 * (r >> 2) + 4 * hi;
                if (kva >= 1101) s0[r] = -1e30f;
                if (kva + 32 >= 1101) s1[r] = -1e30f;
            }
        }

        float t[16];
#pragma unroll
        for (int i = 0; i < 16; ++i) t[i] = fmaxf(s0[i], s1[i]);
        float a0m = f3(t[0], t[1], t[2]),  a1m = f3(t[3], t[4], t[5]);
        float a2m = f3(t[6], t[7], t[8]),  a3m = f3(t[9], t[10], t[11]);
        float a4m = f3(t[12], t[13], t[14]);
        float pm  = fmaxf(f3(a0m, a1m, a2m), f3(a3m, a4m, t[15]));
        float pmax = fmaxf(pm, __shfl_xor(pm, 32));

        if (__any(pmax > mreg + 8.f)) {
            float mn = fmaxf(mreg, pmax);
            float al = exp2_raw(mreg - mn);
            mreg = mn;
            lsum *= al;
#pragma unroll
            for (int i = 0; i < 16; ++i) { o0[i] *= al; o1[i] *= al; }
        }

        unsigned pk0[8], pk1[8];
        float sA = 0.f, sB = 0.f, sC = 0.f, sD = 0.f;
#pragma unroll
        for (int i = 0; i < 8; ++i) {
            float a0 = exp2_raw(s0[2 * i] - mreg), a1 = exp2_raw(s0[2 * i + 1] - mreg);
            float b0 = exp2_raw(s1[2 * i] - mreg), b1 = exp2_raw(s1[2 * i + 1] - mreg);
            pk0[i] = cvt_pk(a0, a1);
            pk1[i] = cvt_pk(b0, b1);
            sA += a0; sB += a1; sC += b0; sD += b1;
        }
        float ls = (sA + sB) + (sC + sD);
        ls += __shfl_xor(ls, 32);
        lsum += ls;

#pragma unroll
        for (int t2 = 0; t2 < 2; ++t2) {
            const unsigned* pk = t2 ? pk1 : pk0;
#pragma unroll
            for (int v = 0; v < 2; ++v) {
                unsigned a0 = pk[4 * v], a1 = pk[4 * v + 1], a2 = pk[4 * v + 2], a3 = pk[4 * v + 3];
                unsigned x = __shfl_xor(hi ? a0 : a2, 32);
                unsigned y = __shfl_xor(hi ? a1 : a3, 32);
                u32x4 fw;
                fw.x = hi ? x : a0; fw.y = hi ? y : a1; fw.z = hi ? a2 : x; fw.w = hi ? a3 : y;
                bf16x8 pf = __builtin_bit_cast(bf16x8, fw);
                const int ks2 = 2 * t2 + v;
                const int sl = ((ks2 * 2 + hi) ^ (ql & 7)) << 3;
                bf16x8 vf0 = *(const bf16x8*)&lds[vb + ql * 64 + sl];
                bf16x8 vf1 = *(const bf16x8*)&lds[vb + (32 + ql) * 64 + sl];
                __builtin_amdgcn_s_setprio(1);
                o0 = mfma32(vf0, pf, o0);
                o1 = mfma32(vf1, pf, o1);
                __builtin_amdgcn_s_setprio(0);
            }
        }

        if (pre) {
            *(uint4*)&lds[(cur ^ 1) * 8192 + w * 512 + lane * 8] = kn;
            *(uint4*)&lds[(cur ^ 1) * 8192 + 4096 + w * 512 + lane * 8] = vn;
        }
        __syncthreads();
        cur ^= 1;
    }

    float rinv = 1.f / lsum;
    unsigned short* sw = &lds[w * 2304];
#pragma unroll
    for (int dt = 0; dt < 2; ++dt) {
#pragma unroll
        for (int rp = 0; rp < 8; ++rp) {
            float e0 = (dt ? o1[2 * rp] : o0[2 * rp]) * rinv;
            float e1 = (dt ? o1[2 * rp + 1] : o0[2 * rp + 1]) * rinv;
            int d = dt * 32 + ((2 * rp) & 3) + 8 * ((2 * rp) >> 2) + 4 * hi;
            *(unsigned*)&sw[ql * 72 + d] = cvt_pk(e0, e1);
        }
    }
    __syncthreads();
    {
        int i = threadIdx.x >> 1, hf = threadIdx.x & 1;
        const unsigned short* src = &lds[(i >> 5) * 2304 + (i & 31) * 72 + hf * 32];
        u32x4 r0 = *(const u32x4*)(src);
        u32x4 r1 = *(const u32x4*)(src + 8);
        u32x4 r2 = *(const u32x4*)(src + 16);
        u32x4 r3 = *(const u32x4*)(src + 24);
        int b = bh >> 3, h = bh & 7;
        unsigned short* gd = atok + ((size_t)b * 1024 + qt * 256 + i) * 512 + h * 64 + hf * 32;
        *(u32x4*)(gd) = r0;
        *(u32x4*)(gd + 8) = r1;
        *(u32x4*)(gd + 16) = r2;
        *(u32x4*)(gd + 24) = r3;
    }
}

extern "C" void kernel_launch(void* const* d_in, const int* in_sizes, int n_in,
                              void* d_out, int out_size, void* d_ws, size_t ws_size,
                              hipStream_t stream) {
    const float* x0     = (const float*)d_in[0];
    const float* cond   = (const float*)d_in[1];
    const float* gamma  = (const float*)d_in[2];
    const float* beta   = (const float*)d_in[3];
    const float* qkv_w  = (const float*)d_in[4];
    const float* qkv_b  = (const float*)d_in[5];
    const float* ckv_w  = (const float*)d_in[6];
    const float* ckv_b  = (const float*)d_in[7];
    const float* out_w  = (const float*)d_in[8];
    const float* out_b  = (const float*)d_in[9];
    float* outp = (float*)d_out;

    char* p = (char*)d_ws;
    float2* part = (float2*)p;           p += 4096;
    unsigned short* xt    = (unsigned short*)p; p += (size_t)16384 * 512 * 2;
    unsigned short* wqkv  = (unsigned short*)p; p += (size_t)1536 * 512 * 2;
    unsigned short* wckv  = (unsigned short*)p; p += (size_t)1024 * 768 * 2;
    unsigned short* wout  = (unsigned short*)p; p += (size_t)512 * 512 * 2;
    unsigned short* condb = (unsigned short*)p; p += (size_t)1232 * 768 * 2;
    unsigned short* Qb    = (unsigned short*)p; p += (size_t)16 * 8 * 1024 * 64 * 2;
    unsigned short* Kb    = (unsigned short*)p; p += (size_t)16 * 8 * KVP * 64 * 2;
    unsigned short* Vtb   = (unsigned short*)p; p += (size_t)16 * 8 * KVP * 64 * 2;
    unsigned short* atok  = (unsigned short*)p; p += (size_t)16384 * 512 * 2;

    prep_k<<<512 + 2716, 256, 0, stream>>>(x0, part, qkv_w, wqkv, ckv_w, wckv, out_w, wout, cond, condb);
    gn_apply_k<<<2048, 256, 0, stream>>>(x0, part, gamma, beta, xt);

    // fused QKV GEMM: y 0..7 -> Q/K, y 8..11 -> V
    gemm256_k<0><<<dim3(64, 12), 512, 0, stream>>>(xt, wqkv, qkv_b, 512,
                                                   Qb, Kb, Vtb, nullptr, nullptr);
    gemm_nt_k<<<dim3(20, 16), 256, 0, stream>>>(condb, wckv, ckv_b, 1232, 1024, 768, Kb, Vtb);
    attn2_k<<<512, 512, 0, stream>>>(Qb, Kb, Vtb, atok);
    gemm256_k<2><<<dim3(64, 4), 512, 0, stream>>>(atok, wout, out_b, 512,
                                                  nullptr, nullptr, nullptr, x0, outp);
}

// Round 14
// 166.588 us; speedup vs baseline: 2.8856x; 1.0351x over previous
//
#include <hip/hip_runtime.h>

typedef short bf16x8 __attribute__((ext_vector_type(8)));
typedef float f32x4 __attribute__((ext_vector_type(4)));
typedef float f32x16 __attribute__((ext_vector_type(16)));
typedef unsigned int u32x4 __attribute__((ext_vector_type(4)));

#define KVP 1152  // 1101 kv rows padded to 18*64

__device__ __forceinline__ unsigned short f2b(float f) {
    unsigned int u = __float_as_uint(f);
    u += 0x7FFFu + ((u >> 16) & 1u);
    return (unsigned short)(u >> 16);
}

__device__ __forceinline__ f32x4 mfma16(bf16x8 a, bf16x8 b, f32x4 c) {
    return __builtin_amdgcn_mfma_f32_16x16x32_bf16(a, b, c, 0, 0, 0);
}
__device__ __forceinline__ f32x16 mfma32(bf16x8 a, bf16x8 b, f32x16 c) {
    return __builtin_amdgcn_mfma_f32_32x32x16_bf16(a, b, c, 0, 0, 0);
}
__device__ __forceinline__ float exp2_raw(float x) {
    float r; asm("v_exp_f32 %0, %1" : "=v"(r) : "v"(x)); return r;
}
__device__ __forceinline__ unsigned cvt_pk(float lo, float hi) {
    unsigned r; asm("v_cvt_pk_bf16_f32 %0, %1, %2" : "=v"(r) : "v"(lo), "v"(hi)); return r;
}
__device__ __forceinline__ float f3(float a, float b, float c) { return fmaxf(fmaxf(a, b), c); }

typedef __attribute__((address_space(3))) unsigned int lds_u32_t;
typedef const __attribute__((address_space(1))) unsigned int glb_u32_t;
__device__ __forceinline__ void async_cp16(const void* g, void* l) {
    __builtin_amdgcn_global_load_lds((glb_u32_t*)(unsigned long long)g,
                                     (lds_u32_t*)(unsigned int)(unsigned long long)l,
                                     16, 0, 0);
}

// ------- fused: GroupNorm partial sums (blocks 0..511) + f32->bf16 converts (rest) -------
__global__ __launch_bounds__(256) void prep_k(const float* __restrict__ x, float2* __restrict__ part,
                                              const float* __restrict__ a, unsigned short* __restrict__ oa,
                                              const float* __restrict__ b, unsigned short* __restrict__ ob,
                                              const float* __restrict__ c, unsigned short* __restrict__ oc,
                                              const float* __restrict__ d, unsigned short* __restrict__ od) {
    if (blockIdx.x < 512) {
        int blk = blockIdx.x;
        const float4* p = (const float4*)(x + (size_t)blk * 16384);
        float s = 0.f, ss = 0.f;
        for (int i = threadIdx.x; i < 4096; i += 256) {
            float4 v = p[i];
            s  += v.x + v.y + v.z + v.w;
            ss += v.x * v.x + v.y * v.y + v.z * v.z + v.w * v.w;
        }
#pragma unroll
        for (int o = 32; o; o >>= 1) { s += __shfl_down(s, o); ss += __shfl_down(ss, o); }
        __shared__ float red[8];
        int w = threadIdx.x >> 6;
        if ((threadIdx.x & 63) == 0) { red[w] = s; red[4 + w] = ss; }
        __syncthreads();
        if (threadIdx.x == 0) {
            s  = red[0] + red[1] + red[2] + red[3];
            ss = red[4] + red[5] + red[6] + red[7];
            part[blk] = make_float2(s, ss);
        }
        return;
    }
    int i = (blockIdx.x - 512) * 256 + threadIdx.x;
    const float* src; unsigned short* dst; int j;
    if (i < 196608)      { src = a; dst = oa; j = i; }
    else if (i < 393216) { src = b; dst = ob; j = i - 196608; }
    else if (i < 458752) { src = c; dst = oc; j = i - 393216; }
    else if (i < 695296) { src = d; dst = od; j = i - 458752; }
    else return;
    float4 v = ((const float4*)src)[j];
    uint2 u = make_uint2(cvt_pk(v.x, v.y), cvt_pk(v.z, v.w));
    ((uint2*)dst)[j] = u;
}

// ------------- GN apply + transpose [B,C,HW] -> bf16 tokens [B,HW,C] (64x64 tiles) -------------
__global__ __launch_bounds__(256) void gn_apply_k(const float* __restrict__ x, const float2* __restrict__ part,
                                                  const float* __restrict__ gamma, const float* __restrict__ beta,
                                                  unsigned short* __restrict__ xt) {
    int st = blockIdx.x & 15;
    int ct = (blockIdx.x >> 4) & 7;
    int b  = blockIdx.x >> 7;
    int bg = b * 8 + ct;
    float2 p0 = part[4 * bg], p1 = part[4 * bg + 1], p2 = part[4 * bg + 2], p3 = part[4 * bg + 3];
    float s = (p0.x + p1.x) + (p2.x + p3.x);
    float ss = (p0.y + p1.y) + (p2.y + p3.y);
    float mean = s * (1.f / 65536.f);
    float var  = ss * (1.f / 65536.f) - mean * mean;
    float rsig = rsqrtf(var + 1e-5f);
    __shared__ unsigned short tile[64][65];
    int tid = threadIdx.x;
#pragma unroll
    for (int it = 0; it < 4; ++it) {
        int idx = it * 256 + tid;
        int ci = idx >> 4, j4 = idx & 15;
        int c = ct * 64 + ci;
        float4 v = *(const float4*)(x + ((size_t)b * 512 + c) * 1024 + st * 64 + j4 * 4);
        float gs = gamma[c] * rsig;
        float bo = beta[c] - mean * gs;
        tile[j4 * 4 + 0][ci] = f2b(v.x * gs + bo);
        tile[j4 * 4 + 1][ci] = f2b(v.y * gs + bo);
        tile[j4 * 4 + 2][ci] = f2b(v.z * gs + bo);
        tile[j4 * 4 + 3][ci] = f2b(v.w * gs + bo);
    }
    __syncthreads();
#pragma unroll
    for (int it = 0; it < 4; ++it) {
        int idx = it * 256 + tid;
        int si = idx >> 4, q = idx & 15;
        uint2 u;
        u.x = (unsigned)tile[si][q * 4 + 0] | ((unsigned)tile[si][q * 4 + 1] << 16);
        u.y = (unsigned)tile[si][q * 4 + 2] | ((unsigned)tile[si][q * 4 + 3] << 16);
        *(uint2*)(xt + ((size_t)b * 1024 + st * 64 + si) * 512 + ct * 64 + q * 4) = u;
    }
}

// ----- 256x128-tile NT GEMM: 8 waves, BK=64, 3 LDS bufs (144KB), depth-1 counted vmcnt,
// ----- single barrier/iter, 32 MFMA/barrier. Discriminating experiment: nT 16 -> 8.
// WAR: stage(t+1)->buf (t+1)%3, last read at t-2; peers' reads(t-2) completed before their
// barrier(t-1) crossing, which the staging wave has also crossed. RAW: own vmcnt(6)+barrier.
// LDS layout: row-major [rows][64], 16B slot s of row r holds global slot s^(r&7) (rule 21).
template <int EPI>
__global__ __launch_bounds__(512) void gemm256_k(const unsigned short* __restrict__ A,
                                                 const unsigned short* __restrict__ Bw,
                                                 const float* __restrict__ bias,
                                                 int K,
                                                 unsigned short* __restrict__ Qo,
                                                 unsigned short* __restrict__ Ko,
                                                 unsigned short* __restrict__ Vo,
                                                 const float* __restrict__ x0,
                                                 float* __restrict__ outp) {
    __shared__ __align__(16) unsigned short As[3][256 * 64];
    __shared__ __align__(16) unsigned short Bs[3][128 * 64];
    const int m0 = blockIdx.x * 256, n0 = blockIdx.y * 128;
    const bool swp = (EPI == 0) && (blockIdx.y < 8);
    const int tid = threadIdx.x, lane = tid & 63, w = tid >> 6;
    const int wr = w >> 1, wc = w & 1;
    const int lc = lane & 15, lg = lane >> 4;

    // staging: lane -> (row8 = lane>>3, slot = lane&7); source slot pre-swizzled ^ (row&7)
    const int r8 = lane >> 3;
    const int sSw = ((lane & 7) ^ (r8 & 7)) * 8;
    const unsigned short* aS = A + (size_t)(m0 + w * 32 + r8) * K + sSw;      // + i*8*K per chunk
    const unsigned short* bS = Bw + (size_t)(n0 + w * 16 + r8) * K + sSw;

    f32x4 acc[4][4];
#pragma unroll
    for (int m = 0; m < 4; ++m)
#pragma unroll
        for (int n = 0; n < 4; ++n) acc[m][n] = (f32x4){0.f, 0.f, 0.f, 0.f};

    const int nT = K >> 6;   // 8 for K=512

#define STAGE64(tile, buf)                                                             \
    {                                                                                  \
        const int k0_ = (tile) << 6;                                                   \
        async_cp16(aS + k0_,                    &As[buf][(w * 32) * 64]);              \
        async_cp16(aS + k0_ + (size_t)8 * K,    &As[buf][(w * 32 + 8) * 64]);          \
        async_cp16(aS + k0_ + (size_t)16 * K,   &As[buf][(w * 32 + 16) * 64]);         \
        async_cp16(aS + k0_ + (size_t)24 * K,   &As[buf][(w * 32 + 24) * 64]);         \
        async_cp16(bS + k0_,                    &Bs[buf][(w * 16) * 64]);              \
        async_cp16(bS + k0_ + (size_t)8 * K,    &Bs[buf][(w * 16 + 8) * 64]);          \
    }

    STAGE64(0, 0);

    int c = 0;
#pragma unroll 1
    for (int t = 0; t < nT; ++t) {
        if (t + 1 < nT) {
            int c1 = c + 1; if (c1 == 3) c1 = 0;
            STAGE64(t + 1, c1);
            asm volatile("s_waitcnt vmcnt(6)" ::: "memory");   // tile t landed (mine)
        } else {
            asm volatile("s_waitcnt vmcnt(0)" ::: "memory");
        }
        __builtin_amdgcn_s_barrier();                          // tile t landed (everyone)

#pragma unroll
        for (int kk = 0; kk < 2; ++kk) {
            bf16x8 af[4], bfr[4];
#pragma unroll
            for (int m = 0; m < 4; ++m) {
                const int row = wr * 64 + m * 16 + lc;
                af[m] = *(const bf16x8*)&As[c][row * 64 + (((kk * 4 + lg) ^ (lc & 7)) * 8)];
            }
#pragma unroll
            for (int n = 0; n < 4; ++n) {
                const int row = wc * 64 + n * 16 + lc;
                bfr[n] = *(const bf16x8*)&Bs[c][row * 64 + (((kk * 4 + lg) ^ (lc & 7)) * 8)];
            }
            __builtin_amdgcn_s_setprio(1);
            if (swp) {
#pragma unroll
                for (int m = 0; m < 4; ++m)
#pragma unroll
                    for (int n = 0; n < 4; ++n)
                        acc[m][n] = mfma16(bfr[n], af[m], acc[m][n]);   // C^T
            } else {
#pragma unroll
                for (int m = 0; m < 4; ++m)
#pragma unroll
                    for (int n = 0; n < 4; ++n)
                        acc[m][n] = mfma16(af[m], bfr[n], acc[m][n]);   // C
            }
            __builtin_amdgcn_s_setprio(0);
        }

        ++c; if (c == 3) c = 0;
    }
#undef STAGE64

    if (EPI == 0) {
        if (swp) {
            const bool isQ = (n0 < 512);
            const float sc = isQ ? (0.125f * 1.44269504089f) : 1.f;
#pragma unroll
            for (int n = 0; n < 4; ++n) {
                const int c0 = n0 + wc * 64 + n * 16 + lg * 4;
                const float4 b4 = *(const float4*)&bias[c0];
#pragma unroll
                for (int m = 0; m < 4; ++m) {
                    const int tok = m0 + wr * 64 + m * 16 + lc;
                    const int b = tok >> 10, l = tok & 1023;
                    float v0 = (acc[m][n][0] + b4.x) * sc;
                    float v1 = (acc[m][n][1] + b4.y) * sc;
                    float v2 = (acc[m][n][2] + b4.z) * sc;
                    float v3 = (acc[m][n][3] + b4.w) * sc;
                    uint2 u = make_uint2(cvt_pk(v0, v1), cvt_pk(v2, v3));
                    if (isQ) {
                        const int hh = c0 >> 6, d = c0 & 63;
                        *(uint2*)(Qo + ((size_t)(b * 8 + hh) * 1024 + l) * 64 + d) = u;
                    } else {
                        const int hh = (c0 - 512) >> 6, d = c0 & 63;
                        *(uint2*)(Ko + ((size_t)(b * 8 + hh) * KVP + l) * 64 + d) = u;
                    }
                }
            }
        } else {
#pragma unroll
            for (int n = 0; n < 4; ++n) {
                const int col = n0 + wc * 64 + n * 16 + lc;
                const int j = col - 1024;
                const int hh = j >> 6, d = j & 63;
                const float bv = bias[col];
#pragma unroll
                for (int m = 0; m < 4; ++m) {
                    const int t0 = m0 + wr * 64 + m * 16 + lg * 4;
                    const int b = t0 >> 10, l0 = t0 & 1023;
                    uint2 u = make_uint2(cvt_pk(acc[m][n][0] + bv, acc[m][n][1] + bv),
                                         cvt_pk(acc[m][n][2] + bv, acc[m][n][3] + bv));
                    *(uint2*)(Vo + ((size_t)(b * 8 + hh) * 64 + d) * KVP + l0) = u;
                }
            }
        }
    } else {
#pragma unroll
        for (int n = 0; n < 4; ++n) {
            const int col = n0 + wc * 64 + n * 16 + lc;
            const float bv = bias[col];
#pragma unroll
            for (int m = 0; m < 4; ++m) {
                const int t0 = m0 + wr * 64 + m * 16 + lg * 4;
                const size_t a = ((size_t)(t0 >> 10) * 512 + col) * 1024 + (t0 & 1023);
                float4 xv = *(const float4*)(x0 + a);
                float4 o;
                o.x = acc[m][n][0] + bv + xv.x;
                o.y = acc[m][n][1] + bv + xv.y;
                o.z = acc[m][n][2] + bv + xv.z;
                o.w = acc[m][n][3] + bv + xv.w;
                *(float4*)(outp + a) = o;
            }
        }
    }
}

// ---------------- 64-tile NT GEMM (cond KV only; M not tile-exact) ----------------
__global__ __launch_bounds__(256) void gemm_nt_k(const unsigned short* __restrict__ A,
                                                 const unsigned short* __restrict__ Bw,
                                                 const float* __restrict__ bias,
                                                 int M, int N, int K,
                                                 unsigned short* __restrict__ Ko,
                                                 unsigned short* __restrict__ Vo) {
    __shared__ unsigned short As[64][40];
    __shared__ unsigned short Bs[64][40];
    const int m0 = blockIdx.x * 64, n0 = blockIdx.y * 64;
    const int tid = threadIdx.x, lane = tid & 63, w = tid >> 6;
    const int lc = lane & 15, lg = lane >> 4;
    const int lrow = tid >> 2, lseg = tid & 3;
    f32x4 acc[4];
#pragma unroll
    for (int i = 0; i < 4; ++i) acc[i] = (f32x4){0.f, 0.f, 0.f, 0.f};

    for (int k0 = 0; k0 < K; k0 += 32) {
        uint4 av = make_uint4(0u, 0u, 0u, 0u);
        if (m0 + lrow < M) av = *(const uint4*)(A + (size_t)(m0 + lrow) * K + k0 + lseg * 8);
        *(uint4*)&As[lrow][lseg * 8] = av;
        uint4 bv = *(const uint4*)(Bw + (size_t)(n0 + lrow) * K + k0 + lseg * 8);
        *(uint4*)&Bs[lrow][lseg * 8] = bv;
        __syncthreads();
        bf16x8 af = *(const bf16x8*)&As[w * 16 + lc][lg * 8];
#pragma unroll
        for (int ct = 0; ct < 4; ++ct) {
            bf16x8 bfr = *(const bf16x8*)&Bs[ct * 16 + lc][lg * 8];
            acc[ct] = mfma16(af, bfr, acc[ct]);
        }
        __syncthreads();
    }

    const int rbase = m0 + w * 16 + lg * 4;
#pragma unroll
    for (int ct = 0; ct < 4; ++ct) {
        int col = n0 + ct * 16 + lc;
        float bv = bias[col];
#pragma unroll
        for (int r = 0; r < 4; ++r) {
            int token = rbase + r;
            if (token >= M) continue;
            float val = acc[ct][r] + bv;
            int b = token / 77, l = token - b * 77;
            if (col < 512) {
                int hh = col >> 6, d = col & 63;
                Ko[((size_t)(b * 8 + hh) * KVP + 1024 + l) * 64 + d] = f2b(val);
            } else {
                int j = col - 512, hh = j >> 6, d = j & 63;
                Vo[((size_t)(b * 8 + hh) * 64 + d) * KVP + 1024 + l] = f2b(val);
            }
        }
    }
}

// ---- attention: 8 waves/block, 32 q-rows/wave, swapped QK^T, KVBLK=64, XCD-friendly decode ----
__global__ __launch_bounds__(512) void attn2_k(const unsigned short* __restrict__ Q,
                                               const unsigned short* __restrict__ Kb,
                                               const unsigned short* __restrict__ Vt,
                                               unsigned short* __restrict__ atok) {
    __shared__ __align__(16) unsigned short lds[18432];

    const int bid = blockIdx.x;
    const int bh = bid & 127;
    const int qt = bid >> 7;
    const int w  = threadIdx.x >> 6;
    const int lane = threadIdx.x & 63;
    const int ql = lane & 31, hi = lane >> 5;
    const int q0 = qt * 256 + w * 32;

    bf16x8 qf[4];
    const unsigned short* Qp = Q + ((size_t)bh * 1024 + q0 + ql) * 64 + hi * 8;
#pragma unroll
    for (int ks = 0; ks < 4; ++ks) qf[ks] = *(const bf16x8*)(Qp + ks * 16);

    const unsigned short* Kg = Kb + (size_t)bh * KVP * 64;
    const unsigned short* Vg = Vt + (size_t)bh * 64 * KVP;

    const int srow = lane >> 3;
    const int sc   = (((lane & 7) ^ (lane >> 3)) << 3);

    f32x16 o0, o1;
#pragma unroll
    for (int i = 0; i < 16; ++i) { o0[i] = 0.f; o1[i] = 0.f; }
    float mreg = -1e30f, lsum = 0.f;

    {
        uint4 kr = *(const uint4*)(Kg + (size_t)(8 * w + srow) * 64 + sc);
        uint4 vr = *(const uint4*)(Vg + (size_t)(8 * w + srow) * KVP + sc);
        *(uint4*)&lds[w * 512 + lane * 8] = kr;
        *(uint4*)&lds[4096 + w * 512 + lane * 8] = vr;
    }
    __syncthreads();

    int cur = 0;
    for (int it = 0; it < 18; ++it) {
        const int kv0 = it * 64;
        const bool pre = (it < 17);
        uint4 kn, vn;
        if (pre) {
            kn = *(const uint4*)(Kg + (size_t)(kv0 + 64 + 8 * w + srow) * 64 + sc);
            vn = *(const uint4*)(Vg + (size_t)(8 * w + srow) * KVP + kv0 + 64 + sc);
        }
        const int kb = cur * 8192, vb = cur * 8192 + 4096;

        f32x16 s0, s1;
#pragma unroll
        for (int i = 0; i < 16; ++i) { s0[i] = 0.f; s1[i] = 0.f; }
        __builtin_amdgcn_s_setprio(1);
#pragma unroll
        for (int ks = 0; ks < 4; ++ks) {
            const int sl = ((ks * 2 + hi) ^ (ql & 7)) << 3;
            bf16x8 kf0 = *(const bf16x8*)&lds[kb + ql * 64 + sl];
            bf16x8 kf1 = *(const bf16x8*)&lds[kb + (32 + ql) * 64 + sl];
            s0 = mfma32(kf0, qf[ks], s0);
            s1 = mfma32(kf1, qf[ks], s1);
        }
        __builtin_amdgcn_s_setprio(0);
        if (kv0 == 1088) {
#pragma unroll
            for (int r = 0; r < 16; ++r) {
                int kva = 1088 + (r & 3) + 8 * (r >> 2) + 4 * hi;
                if (kva >= 1101) s0[r] = -1e30f;
                if (kva + 32 >= 1101) s1[r] = -1e30f;
            }
        }

        float t[16];
#pragma unroll
        for (int i = 0; i < 16; ++i) t[i] = fmaxf(s0[i], s1[i]);
        float a0m = f3(t[0], t[1], t[2]),  a1m = f3(t[3], t[4], t[5]);
        float a2m = f3(t[6], t[7], t[8]),  a3m = f3(t[9], t[10], t[11]);
        float a4m = f3(t[12], t[13], t[14]);
        float pm  = fmaxf(f3(a0m, a1m, a2m), f3(a3m, a4m, t[15]));
        float pmax = fmaxf(pm, __shfl_xor(pm, 32));

        if (__any(pmax > mreg + 8.f)) {
            float mn = fmaxf(mreg, pmax);
            float al = exp2_raw(mreg - mn);
            mreg = mn;
            lsum *= al;
#pragma unroll
            for (int i = 0; i < 16; ++i) { o0[i] *= al; o1[i] *= al; }
        }

        unsigned pk0[8], pk1[8];
        float sA = 0.f, sB = 0.f, sC = 0.f, sD = 0.f;
#pragma unroll
        for (int i = 0; i < 8; ++i) {
            float a0 = exp2_raw(s0[2 * i] - mreg), a1 = exp2_raw(s0[2 * i + 1] - mreg);
            float b0 = exp2_raw(s1[2 * i] - mreg), b1 = exp2_raw(s1[2 * i + 1] - mreg);
            pk0[i] = cvt_pk(a0, a1);
            pk1[i] = cvt_pk(b0, b1);
            sA += a0; sB += a1; sC += b0; sD += b1;
        }
        float ls = (sA + sB) + (sC + sD);
        ls += __shfl_xor(ls, 32);
        lsum += ls;

#pragma unroll
        for (int t2 = 0; t2 < 2; ++t2) {
            const unsigned* pk = t2 ? pk1 : pk0;
#pragma unroll
            for (int v = 0; v < 2; ++v) {
                unsigned a0 = pk[4 * v], a1 = pk[4 * v + 1], a2 = pk[4 * v + 2], a3 = pk[4 * v + 3];
                unsigned x = __shfl_xor(hi ? a0 : a2, 32);
                unsigned y = __shfl_xor(hi ? a1 : a3, 32);
                u32x4 fw;
                fw.x = hi ? x : a0; fw.y = hi ? y : a1; fw.z = hi ? a2 : x; fw.w = hi ? a3 : y;
                bf16x8 pf = __builtin_bit_cast(bf16x8, fw);
                const int ks2 = 2 * t2 + v;
                const int sl = ((ks2 * 2 + hi) ^ (ql & 7)) << 3;
                bf16x8 vf0 = *(const bf16x8*)&lds[vb + ql * 64 + sl];
                bf16x8 vf1 = *(const bf16x8*)&lds[vb + (32 + ql) * 64 + sl];
                __builtin_amdgcn_s_setprio(1);
                o0 = mfma32(vf0, pf, o0);
                o1 = mfma32(vf1, pf, o1);
                __builtin_amdgcn_s_setprio(0);
            }
        }

        if (pre) {
            *(uint4*)&lds[(cur ^ 1) * 8192 + w * 512 + lane * 8] = kn;
            *(uint4*)&lds[(cur ^ 1) * 8192 + 4096 + w * 512 + lane * 8] = vn;
        }
        __syncthreads();
        cur ^= 1;
    }

    float rinv = 1.f / lsum;
    unsigned short* sw = &lds[w * 2304];
#pragma unroll
    for (int dt = 0; dt < 2; ++dt) {
#pragma unroll
        for (int rp = 0; rp < 8; ++rp) {
            float e0 = (dt ? o1[2 * rp] : o0[2 * rp]) * rinv;
            float e1 = (dt ? o1[2 * rp + 1] : o0[2 * rp + 1]) * rinv;
            int d = dt * 32 + ((2 * rp) & 3) + 8 * ((2 * rp) >> 2) + 4 * hi;
            *(unsigned*)&sw[ql * 72 + d] = cvt_pk(e0, e1);
        }
    }
    __syncthreads();
    {
        int i = threadIdx.x >> 1, hf = threadIdx.x & 1;
        const unsigned short* src = &lds[(i >> 5) * 2304 + (i & 31) * 72 + hf * 32];
        u32x4 r0 = *(const u32x4*)(src);
        u32x4 r1 = *(const u32x4*)(src + 8);
        u32x4 r2 = *(const u32x4*)(src + 16);
        u32x4 r3 = *(const u32x4*)(src + 24);
        int b = bh >> 3, h = bh & 7;
        unsigned short* gd = atok + ((size_t)b * 1024 + qt * 256 + i) * 512 + h * 64 + hf * 32;
        *(u32x4*)(gd) = r0;
        *(u32x4*)(gd + 8) = r1;
        *(u32x4*)(gd + 16) = r2;
        *(u32x4*)(gd + 24) = r3;
    }
}

extern "C" void kernel_launch(void* const* d_in, const int* in_sizes, int n_in,
                              void* d_out, int out_size, void* d_ws, size_t ws_size,
                              hipStream_t stream) {
    const float* x0     = (const float*)d_in[0];
    const float* cond   = (const float*)d_in[1];
    const float* gamma  = (const float*)d_in[2];
    const float* beta   = (const float*)d_in[3];
    const float* qkv_w  = (const float*)d_in[4];
    const float* qkv_b  = (const float*)d_in[5];
    const float* ckv_w  = (const float*)d_in[6];
    const float* ckv_b  = (const float*)d_in[7];
    const float* out_w  = (const float*)d_in[8];
    const float* out_b  = (const float*)d_in[9];
    float* outp = (float*)d_out;

    char* p = (char*)d_ws;
    float2* part = (float2*)p;           p += 4096;
    unsigned short* xt    = (unsigned short*)p; p += (size_t)16384 * 512 * 2;
    unsigned short* wqkv  = (unsigned short*)p; p += (size_t)1536 * 512 * 2;
    unsigned short* wckv  = (unsigned short*)p; p += (size_t)1024 * 768 * 2;
    unsigned short* wout  = (unsigned short*)p; p += (size_t)512 * 512 * 2;
    unsigned short* condb = (unsigned short*)p; p += (size_t)1232 * 768 * 2;
    unsigned short* Qb    = (unsigned short*)p; p += (size_t)16 * 8 * 1024 * 64 * 2;
    unsigned short* Kb    = (unsigned short*)p; p += (size_t)16 * 8 * KVP * 64 * 2;
    unsigned short* Vtb   = (unsigned short*)p; p += (size_t)16 * 8 * KVP * 64 * 2;
    unsigned short* atok  = (unsigned short*)p; p += (size_t)16384 * 512 * 2;

    prep_k<<<512 + 2716, 256, 0, stream>>>(x0, part, qkv_w, wqkv, ckv_w, wckv, out_w, wout, cond, condb);
    gn_apply_k<<<2048, 256, 0, stream>>>(x0, part, gamma, beta, xt);

    // fused QKV GEMM: y 0..7 -> Q/K, y 8..11 -> V
    gemm256_k<0><<<dim3(64, 12), 512, 0, stream>>>(xt, wqkv, qkv_b, 512,
                                                   Qb, Kb, Vtb, nullptr, nullptr);
    gemm_nt_k<<<dim3(20, 16), 256, 0, stream>>>(condb, wckv, ckv_b, 1232, 1024, 768, Kb, Vtb);
    attn2_k<<<512, 512, 0, stream>>>(Qb, Kb, Vtb, atok);
    gemm256_k<2><<<dim3(64, 4), 512, 0, stream>>>(atok, wout, out_b, 512,
                                                  nullptr, nullptr, nullptr, x0, outp);
}